// Round 9
// baseline (667.797 us; speedup 1.0000x reference)
//
#include <hip/hip_runtime.h>
#include <hip/hip_bf16.h>

// Transformer-XL RelPartialLearnableMultiHeadAttn forward.
// Inputs: float32 (dict order). Output: FLOAT32. Intermediates bf16 in ws.
// QLEN=512 MLEN=512 KLEN=1024 BSZ=16 NHEAD=16 DHEAD=64
#define QLENC 512
#define MLENC 512
#define KLENC 1024
#define BSZC 16
#define NHEADC 16

typedef __attribute__((ext_vector_type(8))) short bf16x8;
typedef __attribute__((ext_vector_type(4))) float f32x4;

__device__ __forceinline__ float bf2f(short u) {
    union { unsigned u; float f; } c;
    c.u = ((unsigned)(unsigned short)u) << 16;
    return c.f;
}
__device__ __forceinline__ short f2bf(float x) {
    union { float f; unsigned u; } c; c.f = x;
    unsigned r = (c.u + 0x7fffu + ((c.u >> 16) & 1u)) >> 16;
    return (short)r;
}
__device__ __forceinline__ int packbf(float a, float b) {
    return (int)((unsigned)(unsigned short)f2bf(a) | (((unsigned)(unsigned short)f2bf(b)) << 16));
}
__device__ __forceinline__ int pack2(short a, short b) {
    return (int)((unsigned)(unsigned short)a | (((unsigned)(unsigned short)b) << 16));
}

// ---------------------------------------------------------------------------
// Generic 128x128-tile bf16 GEMM, BK=32, 4 waves (2x2), MFMA 16x16x32.
// MODE 0: A = concat(mems,w) f32, B = Wqkv f32; scatter q(+biases)/k/v (bf16)
// MODE 1: A = r f32, B = Wr f32 -> rk[n][jj][d] bf16
// MODE 2: A = ctx bf16, B = Wo f32 -> attn_out f32
template<int MODE>
__launch_bounds__(256, 2)
__global__ void gemm_k(const void* __restrict__ A0v, const void* __restrict__ A1v,
                       const float* __restrict__ B,
                       const float* __restrict__ biasw, const float* __restrict__ biasr,
                       short* __restrict__ o0, short* __restrict__ o1,
                       short* __restrict__ o2, short* __restrict__ o3,
                       float* __restrict__ of,
                       int K, int N)
{
    __shared__ short As[128 * 40];
    __shared__ short Bs[128 * 40];

    const int tid  = threadIdx.x;
    const int lane = tid & 63, wid = tid >> 6;
    const int g = lane >> 4, li = lane & 15;
    const int wr = wid >> 1, wc = wid & 1;
    const int m_base = blockIdx.x * 128, n_base = blockIdx.y * 128;

    f32x4 acc[4][4];
    const f32x4 z4 = {0.f, 0.f, 0.f, 0.f};
#pragma unroll
    for (int a = 0; a < 4; ++a)
#pragma unroll
        for (int c = 0; c < 4; ++c) acc[a][c] = z4;

    const int ar0 = tid >> 2;            // A row within half-tile (0..63)
    const int ac0 = (tid & 3) * 8;       // A col (0,8,16,24)
    const int nt  = tid & 127;           // B: n within tile
    const int kh  = (tid >> 7) * 16;     // B: k half (0 or 16)

    for (int k0 = 0; k0 < K; k0 += 32) {
        int4 aReg[2];
#pragma unroll
        for (int q = 0; q < 2; ++q) {
            int row = m_base + q * 64 + ar0;
            if (MODE == 2) {
                const short* ap = (const short*)A0v + (size_t)row * K;
                aReg[q] = *(const int4*)(ap + k0 + ac0);
            } else {
                const float* ap;
                if (MODE == 0) ap = (row < 8192) ? ((const float*)A0v + (size_t)row * 1024)
                                                 : ((const float*)A1v + (size_t)(row - 8192) * 1024);
                else           ap = (const float*)A0v + (size_t)row * K;
                f32x4 u0 = *(const f32x4*)(ap + k0 + ac0);
                f32x4 u1 = *(const f32x4*)(ap + k0 + ac0 + 4);
                int4 t;
                t.x = packbf(u0[0], u0[1]); t.y = packbf(u0[2], u0[3]);
                t.z = packbf(u1[0], u1[1]); t.w = packbf(u1[2], u1[3]);
                aReg[q] = t;
            }
        }
        const float* bp = B + (size_t)(k0 + kh) * N + n_base + nt;
        float t0 = bp[0],      t1 = bp[N],      t2 = bp[2*N],  t3 = bp[3*N];
        float t4 = bp[4*N],    t5 = bp[5*N],    t6 = bp[6*N],  t7 = bp[7*N];
        float t8 = bp[8*N],    t9 = bp[9*N],    ta = bp[10*N], tb = bp[11*N];
        float tc = bp[12*N],   td = bp[13*N],   te = bp[14*N], tf = bp[15*N];

        __syncthreads();
#pragma unroll
        for (int q = 0; q < 2; ++q)
            *(int4*)&As[(q * 64 + ar0) * 40 + ac0] = aReg[q];
        {
            int4 w0; w0.x = packbf(t0,t1); w0.y = packbf(t2,t3); w0.z = packbf(t4,t5); w0.w = packbf(t6,t7);
            int4 w1; w1.x = packbf(t8,t9); w1.y = packbf(ta,tb); w1.z = packbf(tc,td); w1.w = packbf(te,tf);
            *(int4*)&Bs[nt * 40 + kh]     = w0;
            *(int4*)&Bs[nt * 40 + kh + 8] = w1;
        }
        __syncthreads();

        bf16x8 af[4], bfv[4];
#pragma unroll
        for (int mf = 0; mf < 4; ++mf)
            af[mf] = *(const bf16x8*)&As[(wr * 64 + mf * 16 + li) * 40 + g * 8];
#pragma unroll
        for (int nf = 0; nf < 4; ++nf)
            bfv[nf] = *(const bf16x8*)&Bs[(wc * 64 + nf * 16 + li) * 40 + g * 8];
#pragma unroll
        for (int mf = 0; mf < 4; ++mf)
#pragma unroll
            for (int nf = 0; nf < 4; ++nf)
                acc[mf][nf] = __builtin_amdgcn_mfma_f32_16x16x32_bf16(af[mf], bfv[nf], acc[mf][nf], 0, 0, 0);
    }

    // epilogue (D layout: row = 4*(l>>4)+reg, col = l&15)
#pragma unroll
    for (int mf = 0; mf < 4; ++mf) {
#pragma unroll
        for (int nf = 0; nf < 4; ++nf) {
#pragma unroll
            for (int q = 0; q < 4; ++q) {
                int m   = m_base + wr * 64 + mf * 16 + 4 * g + q;
                int col = n_base + wc * 64 + nf * 16 + li;
                float v = acc[mf][nf][q];
                if (MODE == 0) {
                    int t = m >> 4, b = m & 15;
                    int sec = col >> 10, h = (col >> 6) & 15, d = col & 63;
                    if (sec == 0) {
                        if (t >= MLENC) {
                            int i = t - MLENC;
                            int off = (((b * NHEADC + h) * QLENC + i) << 6) + d;
                            o0[off] = f2bf(v + biasw[h * 64 + d]);
                            o1[off] = f2bf(v + biasr[h * 64 + d]);
                        }
                    } else {
                        int off = (((b * NHEADC + h) * KLENC + t) << 6) + d;
                        if (sec == 1) o2[off] = f2bf(v); else o3[off] = f2bf(v);
                    }
                } else if (MODE == 1) {
                    int h = col >> 6, d = col & 63;
                    o0[((h * KLENC + m) << 6) + d] = f2bf(v);
                } else {
                    of[(size_t)m * 1024 + col] = v;
                }
            }
        }
    }
}

// ---------------------------------------------------------------------------
// Fused rel-attention: grid (8 itiles, 16 heads, 16 batch), 4 waves/block.
// score[i][j] = 0.125*(qw[i].k[j] + qr[i].rk[511+j-i]),  mask j > i+512.
// LDS 36352 B -> 4 blocks/CU. Pl overlays Bd (per-wave private, in-order DS).
__launch_bounds__(256, 2)
__global__ void attn_k(const short* __restrict__ qw, const short* __restrict__ qr,
                       const short* __restrict__ kk, const short* __restrict__ vv,
                       const short* __restrict__ rkm, short* __restrict__ ctx)
{
    __shared__ short Kl[32 * 72];        // K chunk [32 j][64 d] pad->72
    __shared__ short Vt[64 * 40];        // V^T chunk [64 d][32 j] pad->40
    __shared__ short Rl[96 * 72];        // rk rows [96][64] pad->72
    __shared__ float Bd[4][16 * 50];     // per-wave BD [16 r][48 jjc] stride 50 (2-way banks)
    // Pl (per-wave P bf16 [16 r][32 jc] stride 40) overlays Bd[wid]

    const int tid  = threadIdx.x;
    const int lane = tid & 63, wid = tid >> 6;
    const int g = lane >> 4, li = lane & 15;
    const int blk = blockIdx.x, n = blockIdx.y, b = blockIdx.z;
    const int i0 = blk * 64, i0w = i0 + wid * 16;
    const int bn = b * NHEADC + n;

    const short* qwp = qw + (size_t)(bn * QLENC + i0w + li) * 64;
    const short* qrp = qr + (size_t)(bn * QLENC + i0w + li) * 64;
    bf16x8 qwf[2], qrf[2];
    qwf[0] = *(const bf16x8*)(qwp + g * 8);
    qwf[1] = *(const bf16x8*)(qwp + 32 + g * 8);
    qrf[0] = *(const bf16x8*)(qrp + g * 8);
    qrf[1] = *(const bf16x8*)(qrp + 32 + g * 8);

    const f32x4 z4 = {0.f, 0.f, 0.f, 0.f};
    f32x4 o[4];
    float mrun[4], srun[4];
#pragma unroll
    for (int nf = 0; nf < 4; ++nf) o[nf] = z4;
#pragma unroll
    for (int q = 0; q < 4; ++q) { mrun[q] = -1e30f; srun[q] = 0.f; }

    const int sj = tid >> 3, sd = (tid & 7) * 8;
    const int dt = tid & 63, jh = (tid >> 6) * 8;
    const int nch = (i0 + 607) >> 5;

    for (int ch = 0; ch < nch; ++ch) {
        const int j0 = ch * 32;
        int4 kreg = *(const int4*)(kk + (size_t)(bn * KLENC + j0 + sj) * 64 + sd);
        const short* vb = vv + (size_t)(bn * KLENC + j0 + jh) * 64 + dt;
        short va0 = vb[0],      va1 = vb[64],     va2 = vb[2 * 64], va3 = vb[3 * 64];
        short va4 = vb[4 * 64], va5 = vb[5 * 64], va6 = vb[6 * 64], va7 = vb[7 * 64];
        const int jjlo = 448 + j0 - i0;
        int4 rreg[3];
#pragma unroll
        for (int qq = 0; qq < 3; ++qq) {
            int srow = jjlo + qq * 32 + sj;
            if (srow > 1023) srow = 1023;
            rreg[qq] = *(const int4*)(rkm + (size_t)(n * KLENC + srow) * 64 + sd);
        }
        __syncthreads();
        *(int4*)&Kl[sj * 72 + sd] = kreg;
        {
            int4 vw; vw.x = pack2(va0,va1); vw.y = pack2(va2,va3);
            vw.z = pack2(va4,va5); vw.w = pack2(va6,va7);
            *(int4*)&Vt[dt * 40 + jh] = vw;
        }
#pragma unroll
        for (int qq = 0; qq < 3; ++qq)
            *(int4*)&Rl[(qq * 32 + sj) * 72 + sd] = rreg[qq];
        __syncthreads();

        f32x4 sc[2];
#pragma unroll
        for (int nf = 0; nf < 2; ++nf) {
            bf16x8 k0f = *(const bf16x8*)&Kl[(nf * 16 + li) * 72 + g * 8];
            bf16x8 k1f = *(const bf16x8*)&Kl[(nf * 16 + li) * 72 + 32 + g * 8];
            f32x4 t = __builtin_amdgcn_mfma_f32_16x16x32_bf16(qwf[0], k0f, z4, 0, 0, 0);
            sc[nf] = __builtin_amdgcn_mfma_f32_16x16x32_bf16(qwf[1], k1f, t, 0, 0, 0);
        }
        const int rbase = 48 - wid * 16;
        f32x4 bd[3];
#pragma unroll
        for (int nf = 0; nf < 3; ++nf) {
            bf16x8 r0f = *(const bf16x8*)&Rl[(rbase + nf * 16 + li) * 72 + g * 8];
            bf16x8 r1f = *(const bf16x8*)&Rl[(rbase + nf * 16 + li) * 72 + 32 + g * 8];
            f32x4 t = __builtin_amdgcn_mfma_f32_16x16x32_bf16(qrf[0], r0f, z4, 0, 0, 0);
            bd[nf] = __builtin_amdgcn_mfma_f32_16x16x32_bf16(qrf[1], r1f, t, 0, 0, 0);
        }
        float* bdw = &Bd[wid][0];
#pragma unroll
        for (int nf = 0; nf < 3; ++nf)
#pragma unroll
            for (int q = 0; q < 4; ++q)
                bdw[(4 * g + q) * 50 + nf * 16 + li] = bd[nf][q];
        asm volatile("s_waitcnt lgkmcnt(0)" ::: "memory");
        __builtin_amdgcn_sched_barrier(0);

        float av[4], p0v[4], p1v[4];
#pragma unroll
        for (int q = 0; q < 4; ++q) {
            int r = 4 * g + q;
            int i = i0w + r;
            float s0 = (sc[0][q] + bdw[r * 50 + 15 + li - r]) * 0.125f;
            float s1 = (sc[1][q] + bdw[r * 50 + 31 + li - r]) * 0.125f;
            if (j0 + li > i + MLENC)      s0 = -1e30f;
            if (j0 + 16 + li > i + MLENC) s1 = -1e30f;
            float mx = fmaxf(s0, s1);
#pragma unroll
            for (int off = 1; off < 16; off <<= 1) mx = fmaxf(mx, __shfl_xor(mx, off));
            float mnew = fmaxf(mrun[q], mx);
            float p0 = __expf(s0 - mnew);
            float p1 = __expf(s1 - mnew);
            float ps = p0 + p1;
#pragma unroll
            for (int off = 1; off < 16; off <<= 1) ps += __shfl_xor(ps, off);
            float alpha = __expf(mrun[q] - mnew);
            srun[q] = srun[q] * alpha + ps;
            mrun[q] = mnew;
            av[q] = alpha; p0v[q] = p0; p1v[q] = p1;
        }
#pragma unroll
        for (int nf = 0; nf < 4; ++nf)
#pragma unroll
            for (int q = 0; q < 4; ++q) o[nf][q] *= av[q];

        // P -> LDS (overlays Bd[wid]; all Bd reads above are complete in program
        // order; same-wave DS ops execute in order; fence stops compiler reorder)
        asm volatile("" ::: "memory");
        __builtin_amdgcn_sched_barrier(0);
        short* pw = (short*)&Bd[wid][0];
#pragma unroll
        for (int q = 0; q < 4; ++q) {
            pw[(4 * g + q) * 40 + li]      = f2bf(p0v[q]);
            pw[(4 * g + q) * 40 + 16 + li] = f2bf(p1v[q]);
        }
        asm volatile("s_waitcnt lgkmcnt(0)" ::: "memory");
        __builtin_amdgcn_sched_barrier(0);
        bf16x8 pa = *(const bf16x8*)&pw[li * 40 + g * 8];
#pragma unroll
        for (int nf = 0; nf < 4; ++nf) {
            bf16x8 vf = *(const bf16x8*)&Vt[(nf * 16 + li) * 40 + g * 8];
            o[nf] = __builtin_amdgcn_mfma_f32_16x16x32_bf16(pa, vf, o[nf], 0, 0, 0);
        }
    }

    float inv[4];
#pragma unroll
    for (int q = 0; q < 4; ++q) inv[q] = 1.0f / srun[q];
#pragma unroll
    for (int nf = 0; nf < 4; ++nf)
#pragma unroll
        for (int q = 0; q < 4; ++q) {
            int i = i0w + 4 * g + q;
            ctx[(size_t)(i * BSZC + b) * 1024 + n * 64 + nf * 16 + li] = f2bf(o[nf][q] * inv[q]);
        }
}

// ---------------------------------------------------------------------------
// LayerNorm(w + attn_out) * gamma + beta -> FLOAT32 out. One wave per row.
__launch_bounds__(256)
__global__ void ln_k(const float* __restrict__ attn, const float* __restrict__ win,
                     const float* __restrict__ gamma, const float* __restrict__ beta,
                     float* __restrict__ out)
{
    const int wid = threadIdx.x >> 6, lane = threadIdx.x & 63;
    const int m = blockIdx.x * 4 + wid;
    const float* ap = attn + (size_t)m * 1024 + lane * 16;
    const float* wp = win + (size_t)m * 1024 + lane * 16;

    f32x4 A[4], W[4];
#pragma unroll
    for (int t = 0; t < 4; ++t) {
        A[t] = *(const f32x4*)(ap + 4 * t);
        W[t] = *(const f32x4*)(wp + 4 * t);
    }
    float x[16];
#pragma unroll
    for (int t = 0; t < 4; ++t)
#pragma unroll
        for (int c = 0; c < 4; ++c) x[4 * t + c] = A[t][c] + W[t][c];

    float s = 0.f;
#pragma unroll
    for (int e = 0; e < 16; ++e) s += x[e];
#pragma unroll
    for (int off = 1; off < 64; off <<= 1) s += __shfl_xor(s, off);
    float mu = s * (1.0f / 1024.0f);
    float vs = 0.f;
#pragma unroll
    for (int e = 0; e < 16; ++e) { float dd = x[e] - mu; vs += dd * dd; }
#pragma unroll
    for (int off = 1; off < 64; off <<= 1) vs += __shfl_xor(vs, off);
    float rstd = rsqrtf(vs * (1.0f / 1024.0f) + 1e-5f);

    f32x4 G[4], Bt[4];
#pragma unroll
    for (int t = 0; t < 4; ++t) {
        G[t]  = *(const f32x4*)(gamma + lane * 16 + 4 * t);
        Bt[t] = *(const f32x4*)(beta + lane * 16 + 4 * t);
    }
#pragma unroll
    for (int t = 0; t < 4; ++t) {
        f32x4 y;
#pragma unroll
        for (int c = 0; c < 4; ++c)
            y[c] = (x[4 * t + c] - mu) * rstd * G[t][c] + Bt[t][c];
        *(f32x4*)(out + (size_t)m * 1024 + lane * 16 + 4 * t) = y;
    }
}

// ---------------------------------------------------------------------------
extern "C" void kernel_launch(void* const* d_in, const int* in_sizes, int n_in,
                              void* d_out, int out_size, void* d_ws, size_t ws_size,
                              hipStream_t stream)
{
    const float* w     = (const float*)d_in[0];   // [512,16,1024]
    const float* r     = (const float*)d_in[1];   // [1024,1024]
    const float* rwb   = (const float*)d_in[2];   // [16,64]
    const float* rrb   = (const float*)d_in[3];   // [16,64]
    const float* mems  = (const float*)d_in[4];   // [512,16,1024]
    // d_in[5] attn_mask: unused (mask computed analytically: j > i + MLEN)
    const float* Wqkv  = (const float*)d_in[6];   // [1024,3072]
    const float* Wr    = (const float*)d_in[7];   // [1024,1024]
    const float* Wo    = (const float*)d_in[8];   // [1024,1024]
    const float* gamma = (const float*)d_in[9];   // [1024]
    const float* beta  = (const float*)d_in[10];  // [1024]
    float* out = (float*)d_out;                   // FLOAT32 output

    // ws layout (peak 98 MB)
    char* p = (char*)d_ws;
    short* qws = (short*)p; p += (size_t)BSZC * NHEADC * QLENC * 64 * 2;  // 16 MB
    short* qrs = (short*)p; p += (size_t)BSZC * NHEADC * QLENC * 64 * 2;  // 16 MB
    short* kks = (short*)p; p += (size_t)BSZC * NHEADC * KLENC * 64 * 2;  // 32 MB
    short* vvs = (short*)p; p += (size_t)BSZC * NHEADC * KLENC * 64 * 2;  // 32 MB
    short* rks = (short*)p; p += (size_t)NHEADC * KLENC * 64 * 2;         //  2 MB
    short* ctx = (short*)d_out;   // bf16 ctx in d_out's first 16 MB (f32 buffer = 33.5 MB)
    float* att = (float*)d_ws;    // 32 MB alias over qws+qrs (dead after attn_k)

    gemm_k<0><<<dim3(128, 24), 256, 0, stream>>>(mems, w, Wqkv, rwb, rrb,
                                                 qws, qrs, kks, vvs, nullptr, 1024, 3072);
    gemm_k<1><<<dim3(8, 8), 256, 0, stream>>>(r, nullptr, Wr, nullptr, nullptr,
                                              rks, nullptr, nullptr, nullptr, nullptr, 1024, 1024);
    attn_k<<<dim3(8, NHEADC, BSZC), 256, 0, stream>>>(qws, qrs, kks, vvs, rks, ctx);
    gemm_k<2><<<dim3(64, 8), 256, 0, stream>>>(ctx, nullptr, Wo, nullptr, nullptr,
                                               nullptr, nullptr, nullptr, nullptr, att, 1024, 1024);
    ln_k<<<2048, 256, 0, stream>>>(att, w, gamma, beta, out);
}

// Round 10
// 641.981 us; speedup vs baseline: 1.0402x; 1.0402x over previous
//
#include <hip/hip_runtime.h>
#include <hip/hip_bf16.h>

// Transformer-XL RelPartialLearnableMultiHeadAttn forward.
// Inputs: float32 (dict order). Output: FLOAT32. Intermediates bf16 in ws.
// QLEN=512 MLEN=512 KLEN=1024 BSZ=16 NHEAD=16 DHEAD=64
#define QLENC 512
#define MLENC 512
#define KLENC 1024
#define BSZC 16
#define NHEADC 16

typedef __attribute__((ext_vector_type(8))) short bf16x8;
typedef __attribute__((ext_vector_type(4))) float f32x4;

__device__ __forceinline__ float bf2f(short u) {
    union { unsigned u; float f; } c;
    c.u = ((unsigned)(unsigned short)u) << 16;
    return c.f;
}
__device__ __forceinline__ short f2bf(float x) {
    union { float f; unsigned u; } c; c.f = x;
    unsigned r = (c.u + 0x7fffu + ((c.u >> 16) & 1u)) >> 16;
    return (short)r;
}
__device__ __forceinline__ int packbf(float a, float b) {
    return (int)((unsigned)(unsigned short)f2bf(a) | (((unsigned)(unsigned short)f2bf(b)) << 16));
}
__device__ __forceinline__ int pack2(short a, short b) {
    return (int)((unsigned)(unsigned short)a | (((unsigned)(unsigned short)b) << 16));
}

// ---------------------------------------------------------------------------
// Generic 128x128-tile bf16 GEMM, BK=32, 4 waves (2x2), MFMA 16x16x32.
// MODE 0: A = concat(mems,w) f32, B = Wqkv f32; scatter q(+biases)/k/v (bf16)
// MODE 1: A = r f32, B = Wr f32 -> rk[n][jj][d] bf16
// MODE 2: A = ctx bf16, B = Wo f32 -> attn_out f32
template<int MODE>
__launch_bounds__(256)
__global__ void gemm_k(const void* __restrict__ A0v, const void* __restrict__ A1v,
                       const float* __restrict__ B,
                       const float* __restrict__ biasw, const float* __restrict__ biasr,
                       short* __restrict__ o0, short* __restrict__ o1,
                       short* __restrict__ o2, short* __restrict__ o3,
                       float* __restrict__ of,
                       int K, int N)
{
    __shared__ short As[128 * 40];
    __shared__ short Bs[128 * 40];

    const int tid  = threadIdx.x;
    const int lane = tid & 63, wid = tid >> 6;
    const int g = lane >> 4, li = lane & 15;
    const int wr = wid >> 1, wc = wid & 1;
    const int m_base = blockIdx.x * 128, n_base = blockIdx.y * 128;

    f32x4 acc[4][4];
    const f32x4 z4 = {0.f, 0.f, 0.f, 0.f};
#pragma unroll
    for (int a = 0; a < 4; ++a)
#pragma unroll
        for (int c = 0; c < 4; ++c) acc[a][c] = z4;

    const int ar0 = tid >> 2;            // A row within half-tile (0..63)
    const int ac0 = (tid & 3) * 8;       // A col (0,8,16,24)
    const int nt  = tid & 127;           // B: n within tile
    const int kh  = (tid >> 7) * 16;     // B: k half (0 or 16)

    for (int k0 = 0; k0 < K; k0 += 32) {
        int4 aReg[2];
#pragma unroll
        for (int q = 0; q < 2; ++q) {
            int row = m_base + q * 64 + ar0;
            if (MODE == 2) {
                const short* ap = (const short*)A0v + (size_t)row * K;
                aReg[q] = *(const int4*)(ap + k0 + ac0);
            } else {
                const float* ap;
                if (MODE == 0) ap = (row < 8192) ? ((const float*)A0v + (size_t)row * 1024)
                                                 : ((const float*)A1v + (size_t)(row - 8192) * 1024);
                else           ap = (const float*)A0v + (size_t)row * K;
                f32x4 u0 = *(const f32x4*)(ap + k0 + ac0);
                f32x4 u1 = *(const f32x4*)(ap + k0 + ac0 + 4);
                int4 t;
                t.x = packbf(u0[0], u0[1]); t.y = packbf(u0[2], u0[3]);
                t.z = packbf(u1[0], u1[1]); t.w = packbf(u1[2], u1[3]);
                aReg[q] = t;
            }
        }
        const float* bp = B + (size_t)(k0 + kh) * N + n_base + nt;
        float t0 = bp[0],      t1 = bp[N],      t2 = bp[2*N],  t3 = bp[3*N];
        float t4 = bp[4*N],    t5 = bp[5*N],    t6 = bp[6*N],  t7 = bp[7*N];
        float t8 = bp[8*N],    t9 = bp[9*N],    ta = bp[10*N], tb = bp[11*N];
        float tc = bp[12*N],   td = bp[13*N],   te = bp[14*N], tf = bp[15*N];

        __syncthreads();
#pragma unroll
        for (int q = 0; q < 2; ++q)
            *(int4*)&As[(q * 64 + ar0) * 40 + ac0] = aReg[q];
        {
            int4 w0; w0.x = packbf(t0,t1); w0.y = packbf(t2,t3); w0.z = packbf(t4,t5); w0.w = packbf(t6,t7);
            int4 w1; w1.x = packbf(t8,t9); w1.y = packbf(ta,tb); w1.z = packbf(tc,td); w1.w = packbf(te,tf);
            *(int4*)&Bs[nt * 40 + kh]     = w0;
            *(int4*)&Bs[nt * 40 + kh + 8] = w1;
        }
        __syncthreads();

        bf16x8 af[4], bfv[4];
#pragma unroll
        for (int mf = 0; mf < 4; ++mf)
            af[mf] = *(const bf16x8*)&As[(wr * 64 + mf * 16 + li) * 40 + g * 8];
#pragma unroll
        for (int nf = 0; nf < 4; ++nf)
            bfv[nf] = *(const bf16x8*)&Bs[(wc * 64 + nf * 16 + li) * 40 + g * 8];
#pragma unroll
        for (int mf = 0; mf < 4; ++mf)
#pragma unroll
            for (int nf = 0; nf < 4; ++nf)
                acc[mf][nf] = __builtin_amdgcn_mfma_f32_16x16x32_bf16(af[mf], bfv[nf], acc[mf][nf], 0, 0, 0);
    }

    // epilogue (D layout: row = 4*(l>>4)+reg, col = l&15)
#pragma unroll
    for (int mf = 0; mf < 4; ++mf) {
#pragma unroll
        for (int nf = 0; nf < 4; ++nf) {
#pragma unroll
            for (int q = 0; q < 4; ++q) {
                int m   = m_base + wr * 64 + mf * 16 + 4 * g + q;
                int col = n_base + wc * 64 + nf * 16 + li;
                float v = acc[mf][nf][q];
                if (MODE == 0) {
                    int t = m >> 4, b = m & 15;
                    int sec = col >> 10, h = (col >> 6) & 15, d = col & 63;
                    if (sec == 0) {
                        if (t >= MLENC) {
                            int i = t - MLENC;
                            int off = (((b * NHEADC + h) * QLENC + i) << 6) + d;
                            o0[off] = f2bf(v + biasw[h * 64 + d]);
                            o1[off] = f2bf(v + biasr[h * 64 + d]);
                        }
                    } else {
                        int off = (((b * NHEADC + h) * KLENC + t) << 6) + d;
                        if (sec == 1) o2[off] = f2bf(v); else o3[off] = f2bf(v);
                    }
                } else if (MODE == 1) {
                    int h = col >> 6, d = col & 63;
                    o0[((h * KLENC + m) << 6) + d] = f2bf(v);
                } else {
                    of[(size_t)m * 1024 + col] = v;
                }
            }
        }
    }
}

// ---------------------------------------------------------------------------
// Fused rel-attention: grid (8 itiles, 16 heads, 16 batch), 4 waves/block.
// score[i][j] = 0.125*(qw[i].k[j] + qr[i].rk[511+j-i]),  mask j > i+512.
// Rel-shift via in-wave shuffles (no Bd LDS round-trip). LDS ~29 KB.
__launch_bounds__(256)
__global__ void attn_k(const short* __restrict__ qw, const short* __restrict__ qr,
                       const short* __restrict__ kk, const short* __restrict__ vv,
                       const short* __restrict__ rkm, short* __restrict__ ctx)
{
    __shared__ short Kl[32 * 72];        // K chunk [32 j][64 d] pad->72
    __shared__ short Vt[64 * 40];        // V^T chunk [64 d][32 j] pad->40
    __shared__ short Rl[96 * 72];        // rk rows [96][64] pad->72
    __shared__ short Pl[4][16 * 44];     // per-wave P bf16 [16 r][32 jc] stride 44

    const int tid  = threadIdx.x;
    const int lane = tid & 63, wid = tid >> 6;
    const int g = lane >> 4, li = lane & 15;
    const int blk = blockIdx.x, n = blockIdx.y, b = blockIdx.z;
    const int i0 = blk * 64, i0w = i0 + wid * 16;
    const int bn = b * NHEADC + n;

    const short* qwp = qw + (size_t)(bn * QLENC + i0w + li) * 64;
    const short* qrp = qr + (size_t)(bn * QLENC + i0w + li) * 64;
    bf16x8 qwf[2], qrf[2];
    qwf[0] = *(const bf16x8*)(qwp + g * 8);
    qwf[1] = *(const bf16x8*)(qwp + 32 + g * 8);
    qrf[0] = *(const bf16x8*)(qrp + g * 8);
    qrf[1] = *(const bf16x8*)(qrp + 32 + g * 8);

    const f32x4 z4 = {0.f, 0.f, 0.f, 0.f};
    f32x4 o[4];
    float mrun[4], srun[4];
#pragma unroll
    for (int nf = 0; nf < 4; ++nf) o[nf] = z4;
#pragma unroll
    for (int q = 0; q < 4; ++q) { mrun[q] = -1e30f; srun[q] = 0.f; }

    const int sj = tid >> 3, sd = (tid & 7) * 8;
    const int dt = tid & 63, jh = (tid >> 6) * 8;
    const int nch = (i0 + 607) >> 5;

    for (int ch = 0; ch < nch; ++ch) {
        const int j0 = ch * 32;
        int4 kreg = *(const int4*)(kk + (size_t)(bn * KLENC + j0 + sj) * 64 + sd);
        const short* vb = vv + (size_t)(bn * KLENC + j0 + jh) * 64 + dt;
        short va0 = vb[0],      va1 = vb[64],     va2 = vb[2 * 64], va3 = vb[3 * 64];
        short va4 = vb[4 * 64], va5 = vb[5 * 64], va6 = vb[6 * 64], va7 = vb[7 * 64];
        const int jjlo = 448 + j0 - i0;
        int4 rreg[3];
#pragma unroll
        for (int qq = 0; qq < 3; ++qq) {
            int srow = jjlo + qq * 32 + sj;
            if (srow > 1023) srow = 1023;
            rreg[qq] = *(const int4*)(rkm + (size_t)(n * KLENC + srow) * 64 + sd);
        }
        __syncthreads();
        *(int4*)&Kl[sj * 72 + sd] = kreg;
        {
            int4 vw; vw.x = pack2(va0,va1); vw.y = pack2(va2,va3);
            vw.z = pack2(va4,va5); vw.w = pack2(va6,va7);
            *(int4*)&Vt[dt * 40 + jh] = vw;
        }
#pragma unroll
        for (int qq = 0; qq < 3; ++qq)
            *(int4*)&Rl[(qq * 32 + sj) * 72 + sd] = rreg[qq];
        __syncthreads();

        // ---- AC = qw . K^T  (2 col-tiles, K-dim 64)
        f32x4 sc[2];
#pragma unroll
        for (int nf = 0; nf < 2; ++nf) {
            bf16x8 k0f = *(const bf16x8*)&Kl[(nf * 16 + li) * 72 + g * 8];
            bf16x8 k1f = *(const bf16x8*)&Kl[(nf * 16 + li) * 72 + 32 + g * 8];
            f32x4 t = __builtin_amdgcn_mfma_f32_16x16x32_bf16(qwf[0], k0f, z4, 0, 0, 0);
            sc[nf] = __builtin_amdgcn_mfma_f32_16x16x32_bf16(qwf[1], k1f, t, 0, 0, 0);
        }
        // ---- BD_raw over 48-wide jj window (3 col-tiles)
        const int rbase = 48 - wid * 16;
        f32x4 bd[3];
#pragma unroll
        for (int nf = 0; nf < 3; ++nf) {
            bf16x8 r0f = *(const bf16x8*)&Rl[(rbase + nf * 16 + li) * 72 + g * 8];
            bf16x8 r1f = *(const bf16x8*)&Rl[(rbase + nf * 16 + li) * 72 + 32 + g * 8];
            f32x4 t = __builtin_amdgcn_mfma_f32_16x16x32_bf16(qrf[0], r0f, z4, 0, 0, 0);
            bd[nf] = __builtin_amdgcn_mfma_f32_16x16x32_bf16(qrf[1], r1f, t, 0, 0, 0);
        }

        // ---- rel-shift via shuffle: value(row r, col cc) lives in lane
        // (lane&48)|(cc&15), register q — same g-group, same register.
        float av[4], p0v[4], p1v[4];
#pragma unroll
        for (int q = 0; q < 4; ++q) {
            int r  = 4 * g + q;
            int i  = i0w + r;
            int cc = 15 + li - r;                    // [0,30]
            int src = (lane & 48) | (cc & 15);
            float b0 = __shfl(bd[0][q], src);
            float b1 = __shfl(bd[1][q], src);
            float b2 = __shfl(bd[2][q], src);
            float bd0 = (cc < 16) ? b0 : b1;         // s0: window col cc
            float bd1 = (cc < 16) ? b1 : b2;         // s1: window col cc+16
            float s0 = (sc[0][q] + bd0) * 0.125f;
            float s1 = (sc[1][q] + bd1) * 0.125f;
            if (j0 + li > i + MLENC)      s0 = -1e30f;
            if (j0 + 16 + li > i + MLENC) s1 = -1e30f;
            float mx = fmaxf(s0, s1);
#pragma unroll
            for (int off = 1; off < 16; off <<= 1) mx = fmaxf(mx, __shfl_xor(mx, off));
            float mnew = fmaxf(mrun[q], mx);
            float p0 = __expf(s0 - mnew);
            float p1 = __expf(s1 - mnew);
            float ps = p0 + p1;
#pragma unroll
            for (int off = 1; off < 16; off <<= 1) ps += __shfl_xor(ps, off);
            float alpha = __expf(mrun[q] - mnew);
            srun[q] = srun[q] * alpha + ps;
            mrun[q] = mnew;
            av[q] = alpha; p0v[q] = p0; p1v[q] = p1;
        }
#pragma unroll
        for (int nf = 0; nf < 4; ++nf)
#pragma unroll
            for (int q = 0; q < 4; ++q) o[nf][q] *= av[q];

        // ---- P -> LDS (D-layout scatter), read back as A-frag
        short* pw = &Pl[wid][0];
#pragma unroll
        for (int q = 0; q < 4; ++q) {
            pw[(4 * g + q) * 44 + li]      = f2bf(p0v[q]);
            pw[(4 * g + q) * 44 + 16 + li] = f2bf(p1v[q]);
        }
        bf16x8 pa = *(const bf16x8*)&pw[li * 44 + g * 8];
#pragma unroll
        for (int nf = 0; nf < 4; ++nf) {
            bf16x8 vf = *(const bf16x8*)&Vt[(nf * 16 + li) * 40 + g * 8];
            o[nf] = __builtin_amdgcn_mfma_f32_16x16x32_bf16(pa, vf, o[nf], 0, 0, 0);
        }
    }

    float inv[4];
#pragma unroll
    for (int q = 0; q < 4; ++q) inv[q] = 1.0f / srun[q];
#pragma unroll
    for (int nf = 0; nf < 4; ++nf)
#pragma unroll
        for (int q = 0; q < 4; ++q) {
            int i = i0w + 4 * g + q;
            ctx[(size_t)(i * BSZC + b) * 1024 + n * 64 + nf * 16 + li] = f2bf(o[nf][q] * inv[q]);
        }
}

// ---------------------------------------------------------------------------
// LayerNorm(w + attn_out) * gamma + beta -> FLOAT32 out. One wave per row.
__launch_bounds__(256)
__global__ void ln_k(const float* __restrict__ attn, const float* __restrict__ win,
                     const float* __restrict__ gamma, const float* __restrict__ beta,
                     float* __restrict__ out)
{
    const int wid = threadIdx.x >> 6, lane = threadIdx.x & 63;
    const int m = blockIdx.x * 4 + wid;
    const float* ap = attn + (size_t)m * 1024 + lane * 16;
    const float* wp = win + (size_t)m * 1024 + lane * 16;

    f32x4 A[4], W[4];
#pragma unroll
    for (int t = 0; t < 4; ++t) {
        A[t] = *(const f32x4*)(ap + 4 * t);
        W[t] = *(const f32x4*)(wp + 4 * t);
    }
    float x[16];
#pragma unroll
    for (int t = 0; t < 4; ++t)
#pragma unroll
        for (int c = 0; c < 4; ++c) x[4 * t + c] = A[t][c] + W[t][c];

    float s = 0.f;
#pragma unroll
    for (int e = 0; e < 16; ++e) s += x[e];
#pragma unroll
    for (int off = 1; off < 64; off <<= 1) s += __shfl_xor(s, off);
    float mu = s * (1.0f / 1024.0f);
    float vs = 0.f;
#pragma unroll
    for (int e = 0; e < 16; ++e) { float dd = x[e] - mu; vs += dd * dd; }
#pragma unroll
    for (int off = 1; off < 64; off <<= 1) vs += __shfl_xor(vs, off);
    float rstd = rsqrtf(vs * (1.0f / 1024.0f) + 1e-5f);

    f32x4 G[4], Bt[4];
#pragma unroll
    for (int t = 0; t < 4; ++t) {
        G[t]  = *(const f32x4*)(gamma + lane * 16 + 4 * t);
        Bt[t] = *(const f32x4*)(beta + lane * 16 + 4 * t);
    }
#pragma unroll
    for (int t = 0; t < 4; ++t) {
        f32x4 y;
#pragma unroll
        for (int c = 0; c < 4; ++c)
            y[c] = (x[4 * t + c] - mu) * rstd * G[t][c] + Bt[t][c];
        *(f32x4*)(out + (size_t)m * 1024 + lane * 16 + 4 * t) = y;
    }
}

// ---------------------------------------------------------------------------
extern "C" void kernel_launch(void* const* d_in, const int* in_sizes, int n_in,
                              void* d_out, int out_size, void* d_ws, size_t ws_size,
                              hipStream_t stream)
{
    const float* w     = (const float*)d_in[0];   // [512,16,1024]
    const float* r     = (const float*)d_in[1];   // [1024,1024]
    const float* rwb   = (const float*)d_in[2];   // [16,64]
    const float* rrb   = (const float*)d_in[3];   // [16,64]
    const float* mems  = (const float*)d_in[4];   // [512,16,1024]
    // d_in[5] attn_mask: unused (mask computed analytically: j > i + MLEN)
    const float* Wqkv  = (const float*)d_in[6];   // [1024,3072]
    const float* Wr    = (const float*)d_in[7];   // [1024,1024]
    const float* Wo    = (const float*)d_in[8];   // [1024,1024]
    const float* gamma = (const float*)d_in[9];   // [1024]
    const float* beta  = (const float*)d_in[10];  // [1024]
    float* out = (float*)d_out;                   // FLOAT32 output

    // ws layout (peak 98 MB)
    char* p = (char*)d_ws;
    short* qws = (short*)p; p += (size_t)BSZC * NHEADC * QLENC * 64 * 2;  // 16 MB
    short* qrs = (short*)p; p += (size_t)BSZC * NHEADC * QLENC * 64 * 2;  // 16 MB
    short* kks = (short*)p; p += (size_t)BSZC * NHEADC * KLENC * 64 * 2;  // 32 MB
    short* vvs = (short*)p; p += (size_t)BSZC * NHEADC * KLENC * 64 * 2;  // 32 MB
    short* rks = (short*)p; p += (size_t)NHEADC * KLENC * 64 * 2;         //  2 MB
    short* ctx = (short*)d_out;   // bf16 ctx in d_out's first 16 MB (f32 buffer = 33.5 MB)
    float* att = (float*)d_ws;    // 32 MB alias over qws+qrs (dead after attn_k)

    gemm_k<0><<<dim3(128, 24), 256, 0, stream>>>(mems, w, Wqkv, rwb, rrb,
                                                 qws, qrs, kks, vvs, nullptr, 1024, 3072);
    gemm_k<1><<<dim3(8, 8), 256, 0, stream>>>(r, nullptr, Wr, nullptr, nullptr,
                                              rks, nullptr, nullptr, nullptr, nullptr, 1024, 1024);
    attn_k<<<dim3(8, NHEADC, BSZC), 256, 0, stream>>>(qws, qrs, kks, vvs, rks, ctx);
    gemm_k<2><<<dim3(64, 8), 256, 0, stream>>>(ctx, nullptr, Wo, nullptr, nullptr,
                                               nullptr, nullptr, nullptr, nullptr, att, 1024, 1024);
    ln_k<<<2048, 256, 0, stream>>>(att, w, gamma, beta, out);
}

// Round 11
// 574.407 us; speedup vs baseline: 1.1626x; 1.1176x over previous
//
#include <hip/hip_runtime.h>
#include <hip/hip_bf16.h>

// Transformer-XL RelPartialLearnableMultiHeadAttn forward.
// Inputs: float32 (dict order). Output: FLOAT32. Intermediates bf16 in ws.
// QLEN=512 MLEN=512 KLEN=1024 BSZ=16 NHEAD=16 DHEAD=64
#define QLENC 512
#define MLENC 512
#define KLENC 1024
#define BSZC 16
#define NHEADC 16

typedef __attribute__((ext_vector_type(8))) short bf16x8;
typedef __attribute__((ext_vector_type(4))) float f32x4;

__device__ __forceinline__ float bf2f(short u) {
    union { unsigned u; float f; } c;
    c.u = ((unsigned)(unsigned short)u) << 16;
    return c.f;
}
__device__ __forceinline__ short f2bf(float x) {
    union { float f; unsigned u; } c; c.f = x;
    unsigned r = (c.u + 0x7fffu + ((c.u >> 16) & 1u)) >> 16;
    return (short)r;
}
__device__ __forceinline__ int packbf(float a, float b) {
    return (int)((unsigned)(unsigned short)f2bf(a) | (((unsigned)(unsigned short)f2bf(b)) << 16));
}
__device__ __forceinline__ int pack2(short a, short b) {
    return (int)((unsigned)(unsigned short)a | (((unsigned)(unsigned short)b) << 16));
}

// Direct HBM->LDS 16B load (CK-style addrspace casts).
__device__ __forceinline__ void gload_lds16(const void* g, void* l) {
    auto* gp = reinterpret_cast<const __attribute__((address_space(1))) unsigned int*>(
        reinterpret_cast<unsigned long long>(g));
    auto* lp = reinterpret_cast<__attribute__((address_space(3))) unsigned int*>(
        reinterpret_cast<unsigned long long>(l));
    __builtin_amdgcn_global_load_lds(gp, lp, 16, 0, 0);
}

// ---------------------------------------------------------------------------
// Generic 128x128-tile bf16 GEMM, BK=32, 4 waves (2x2), MFMA 16x16x32.
// MODE 0: A = concat(mems,w) f32, B = Wqkv f32; scatter q(+biases)/k/v (bf16)
// MODE 1: A = r f32, B = Wr f32 -> rk[n][jj][d] bf16
// MODE 2: A = ctx bf16, B = Wo f32 -> attn_out f32
template<int MODE>
__launch_bounds__(256)
__global__ void gemm_k(const void* __restrict__ A0v, const void* __restrict__ A1v,
                       const float* __restrict__ B,
                       const float* __restrict__ biasw, const float* __restrict__ biasr,
                       short* __restrict__ o0, short* __restrict__ o1,
                       short* __restrict__ o2, short* __restrict__ o3,
                       float* __restrict__ of,
                       int K, int N)
{
    __shared__ short As[128 * 40];
    __shared__ short Bs[128 * 40];

    const int tid  = threadIdx.x;
    const int lane = tid & 63, wid = tid >> 6;
    const int g = lane >> 4, li = lane & 15;
    const int wr = wid >> 1, wc = wid & 1;
    const int m_base = blockIdx.x * 128, n_base = blockIdx.y * 128;

    f32x4 acc[4][4];
    const f32x4 z4 = {0.f, 0.f, 0.f, 0.f};
#pragma unroll
    for (int a = 0; a < 4; ++a)
#pragma unroll
        for (int c = 0; c < 4; ++c) acc[a][c] = z4;

    const int ar0 = tid >> 2;            // A row within half-tile (0..63)
    const int ac0 = (tid & 3) * 8;       // A col (0,8,16,24)
    const int nt  = tid & 127;           // B: n within tile
    const int kh  = (tid >> 7) * 16;     // B: k half (0 or 16)

    for (int k0 = 0; k0 < K; k0 += 32) {
        int4 aReg[2];
#pragma unroll
        for (int q = 0; q < 2; ++q) {
            int row = m_base + q * 64 + ar0;
            if (MODE == 2) {
                const short* ap = (const short*)A0v + (size_t)row * K;
                aReg[q] = *(const int4*)(ap + k0 + ac0);
            } else {
                const float* ap;
                if (MODE == 0) ap = (row < 8192) ? ((const float*)A0v + (size_t)row * 1024)
                                                 : ((const float*)A1v + (size_t)(row - 8192) * 1024);
                else           ap = (const float*)A0v + (size_t)row * K;
                f32x4 u0 = *(const f32x4*)(ap + k0 + ac0);
                f32x4 u1 = *(const f32x4*)(ap + k0 + ac0 + 4);
                int4 t;
                t.x = packbf(u0[0], u0[1]); t.y = packbf(u0[2], u0[3]);
                t.z = packbf(u1[0], u1[1]); t.w = packbf(u1[2], u1[3]);
                aReg[q] = t;
            }
        }
        const float* bp = B + (size_t)(k0 + kh) * N + n_base + nt;
        float t0 = bp[0],      t1 = bp[N],      t2 = bp[2*N],  t3 = bp[3*N];
        float t4 = bp[4*N],    t5 = bp[5*N],    t6 = bp[6*N],  t7 = bp[7*N];
        float t8 = bp[8*N],    t9 = bp[9*N],    ta = bp[10*N], tb = bp[11*N];
        float tc = bp[12*N],   td = bp[13*N],   te = bp[14*N], tf = bp[15*N];

        __syncthreads();
#pragma unroll
        for (int q = 0; q < 2; ++q)
            *(int4*)&As[(q * 64 + ar0) * 40 + ac0] = aReg[q];
        {
            int4 w0; w0.x = packbf(t0,t1); w0.y = packbf(t2,t3); w0.z = packbf(t4,t5); w0.w = packbf(t6,t7);
            int4 w1; w1.x = packbf(t8,t9); w1.y = packbf(ta,tb); w1.z = packbf(tc,td); w1.w = packbf(te,tf);
            *(int4*)&Bs[nt * 40 + kh]     = w0;
            *(int4*)&Bs[nt * 40 + kh + 8] = w1;
        }
        __syncthreads();

        bf16x8 af[4], bfv[4];
#pragma unroll
        for (int mf = 0; mf < 4; ++mf)
            af[mf] = *(const bf16x8*)&As[(wr * 64 + mf * 16 + li) * 40 + g * 8];
#pragma unroll
        for (int nf = 0; nf < 4; ++nf)
            bfv[nf] = *(const bf16x8*)&Bs[(wc * 64 + nf * 16 + li) * 40 + g * 8];
#pragma unroll
        for (int mf = 0; mf < 4; ++mf)
#pragma unroll
            for (int nf = 0; nf < 4; ++nf)
                acc[mf][nf] = __builtin_amdgcn_mfma_f32_16x16x32_bf16(af[mf], bfv[nf], acc[mf][nf], 0, 0, 0);
    }

    // epilogue (D layout: row = 4*(l>>4)+reg, col = l&15)
#pragma unroll
    for (int mf = 0; mf < 4; ++mf) {
#pragma unroll
        for (int nf = 0; nf < 4; ++nf) {
#pragma unroll
            for (int q = 0; q < 4; ++q) {
                int m   = m_base + wr * 64 + mf * 16 + 4 * g + q;
                int col = n_base + wc * 64 + nf * 16 + li;
                float v = acc[mf][nf][q];
                if (MODE == 0) {
                    int t = m >> 4, b = m & 15;
                    int sec = col >> 10, h = (col >> 6) & 15, d = col & 63;
                    if (sec == 0) {
                        if (t >= MLENC) {
                            int i = t - MLENC;
                            int off = (((b * NHEADC + h) * QLENC + i) << 6) + d;
                            o0[off] = f2bf(v + biasw[h * 64 + d]);
                            o1[off] = f2bf(v + biasr[h * 64 + d]);
                        }
                    } else {
                        int off = (((b * NHEADC + h) * KLENC + t) << 6) + d;
                        if (sec == 1) o2[off] = f2bf(v); else o3[off] = f2bf(v);
                    }
                } else if (MODE == 1) {
                    int h = col >> 6, d = col & 63;
                    o0[((h * KLENC + m) << 6) + d] = f2bf(v);
                } else {
                    of[(size_t)m * 1024 + col] = v;
                }
            }
        }
    }
}

// ---------------------------------------------------------------------------
// Fused rel-attention, restructured staging:
//  - K: double-buffered linear [32][64] LDS via global_load_lds, XOR chunk
//    swizzle on the GLOBAL source (phys16Bchunk = logical ^ (row&7)).
//  - R: circular 128-row linear LDS window via global_load_lds (same swizzle);
//    stage 32 new rows/chunk.
//  - V: register transpose -> double-buffered Vt (16B live regs).
//  - ONE barrier per chunk; prefetch ch+1 issued right after it.
// score[i][j] = 0.125*(qw[i].k[j] + qr[i].rk[511+j-i]),  mask j > i+512.
__launch_bounds__(256)
__global__ void attn_k(const short* __restrict__ qw, const short* __restrict__ qr,
                       const short* __restrict__ kk, const short* __restrict__ vv,
                       const short* __restrict__ rkm, short* __restrict__ ctx)
{
    __shared__ short Kb[2][32 * 64];     // 8 KB, linear, swizzled content
    __shared__ short Rl[128 * 64];       // 16 KB circular, swizzled content
    __shared__ short Vt[2][64 * 40];     // 10 KB
    __shared__ short Pl[4][16 * 44];     // 5.5 KB per-wave P

    const int tid  = threadIdx.x;
    const int lane = tid & 63, wid = tid >> 6;
    const int g = lane >> 4, li = lane & 15;
    const int blk = blockIdx.x, n = blockIdx.y, b = blockIdx.z;
    const int i0 = blk * 64, i0w = i0 + wid * 16;
    const int bn = b * NHEADC + n;
    const int jjlo0 = 448 - i0;          // jj of Rl logical row 0 (>=0)

    // staging lane decomposition
    const int l8 = lane >> 3;            // row-in-8 group
    const int l7 = lane & 7;             // physical 16B chunk
    const int lc = l7 ^ l8;              // logical chunk to fetch (row&7 == l8)
    const int dt = tid & 63, jh = wid * 8;  // V transpose coords

    const short* qwp = qw + (size_t)(bn * QLENC + i0w + li) * 64;
    const short* qrp = qr + (size_t)(bn * QLENC + i0w + li) * 64;
    bf16x8 qwf[2], qrf[2];
    qwf[0] = *(const bf16x8*)(qwp + g * 8);
    qwf[1] = *(const bf16x8*)(qwp + 32 + g * 8);
    qrf[0] = *(const bf16x8*)(qrp + g * 8);
    qrf[1] = *(const bf16x8*)(qrp + 32 + g * 8);

    const f32x4 z4 = {0.f, 0.f, 0.f, 0.f};
    f32x4 o[4];
    float mrun[4], srun[4];
#pragma unroll
    for (int nf = 0; nf < 4; ++nf) o[nf] = z4;
#pragma unroll
    for (int q = 0; q < 4; ++q) { mrun[q] = -1e30f; srun[q] = 0.f; }

    const int nch = (i0 + 607) >> 5;     // 2*blk + 18
    const int pswz = (g ^ (li & 7)) * 8; // swizzled read offset (shorts)
    const int rbase = 48 - wid * 16;

    // ---------------- prologue: stage chunk 0 ----------------
    // K(0): wave wid stages rows 8*wid .. 8*wid+7
    gload_lds16(kk + ((size_t)bn * 1024 + 8 * wid + l8) * 64 + lc * 8,
                &Kb[0][wid * 512]);
    // R rows [0,96): wave wid stages rows {32q + 8*wid + l8}, q=0..2
#pragma unroll
    for (int q = 0; q < 3; ++q) {
        int lr = 32 * q + 8 * wid + l8;
        int srow = jjlo0 + lr; if (srow > 1023) srow = 1023;
        gload_lds16(rkm + ((size_t)n * 1024 + srow) * 64 + lc * 8,
                    &Rl[((32 * q + 8 * wid) & 127) * 64]);
    }
    // V(0) -> regs
    short va0, va1, va2, va3, va4, va5, va6, va7;
    {
        const short* vb = vv + ((size_t)bn * 1024 + jh) * 64 + dt;
        va0 = vb[0];      va1 = vb[64];     va2 = vb[2 * 64]; va3 = vb[3 * 64];
        va4 = vb[4 * 64]; va5 = vb[5 * 64]; va6 = vb[6 * 64]; va7 = vb[7 * 64];
    }
    int cur = 0;

    for (int ch = 0; ch < nch; ++ch) {
        const int j0 = ch * 32;
        // 1. V(ch) regs -> Vt[cur] (other waves may still compute ch-1 on [cur^1])
        {
            int4 vw; vw.x = pack2(va0, va1); vw.y = pack2(va2, va3);
            vw.z = pack2(va4, va5); vw.w = pack2(va6, va7);
            *(int4*)&Vt[cur][dt * 40 + jh] = vw;
        }
        // 2. my staged K/R for chunk ch have landed
        asm volatile("s_waitcnt vmcnt(0)" ::: "memory");
        // 3. all waves: staging visible, compute(ch-1) retired
        __syncthreads();
        // 4. prefetch chunk ch+1 (hides under compute(ch))
        if (ch + 1 < nch) {
            const int j0n = j0 + 32;
            gload_lds16(kk + ((size_t)bn * 1024 + j0n + 8 * wid + l8) * 64 + lc * 8,
                        &Kb[cur ^ 1][wid * 512]);
            int lr = 96 + 32 * ch + 8 * wid + l8;
            int srow = jjlo0 + lr; if (srow > 1023) srow = 1023;
            gload_lds16(rkm + ((size_t)n * 1024 + srow) * 64 + lc * 8,
                        &Rl[((96 + 32 * ch + 8 * wid) & 127) * 64]);
            const short* vb = vv + ((size_t)bn * 1024 + j0n + jh) * 64 + dt;
            va0 = vb[0];      va1 = vb[64];     va2 = vb[2 * 64]; va3 = vb[3 * 64];
            va4 = vb[4 * 64]; va5 = vb[5 * 64]; va6 = vb[6 * 64]; va7 = vb[7 * 64];
        }

        // 5. compute chunk ch
        const short* kbuf = &Kb[cur][0];
        f32x4 sc[2];
#pragma unroll
        for (int nf = 0; nf < 2; ++nf) {
            bf16x8 k0f = *(const bf16x8*)&kbuf[(nf * 16 + li) * 64 + pswz];
            bf16x8 k1f = *(const bf16x8*)&kbuf[(nf * 16 + li) * 64 + (pswz ^ 32)];
            f32x4 t = __builtin_amdgcn_mfma_f32_16x16x32_bf16(qwf[0], k0f, z4, 0, 0, 0);
            sc[nf] = __builtin_amdgcn_mfma_f32_16x16x32_bf16(qwf[1], k1f, t, 0, 0, 0);
        }
        const int rsh = 32 * ch;
        f32x4 bd[3];
#pragma unroll
        for (int nf = 0; nf < 3; ++nf) {
            int prow = (rbase + nf * 16 + li + rsh) & 127;
            bf16x8 r0f = *(const bf16x8*)&Rl[prow * 64 + pswz];
            bf16x8 r1f = *(const bf16x8*)&Rl[prow * 64 + (pswz ^ 32)];
            f32x4 t = __builtin_amdgcn_mfma_f32_16x16x32_bf16(qrf[0], r0f, z4, 0, 0, 0);
            bd[nf] = __builtin_amdgcn_mfma_f32_16x16x32_bf16(qrf[1], r1f, t, 0, 0, 0);
        }

        // rel-shift via shuffle: BD(row r, window col cc) sits in lane
        // (lane&48)|(cc&15), register q
        float av[4], p0v[4], p1v[4];
#pragma unroll
        for (int q = 0; q < 4; ++q) {
            int r  = 4 * g + q;
            int i  = i0w + r;
            int cc = 15 + li - r;
            int src = (lane & 48) | (cc & 15);
            float b0 = __shfl(bd[0][q], src);
            float b1 = __shfl(bd[1][q], src);
            float b2 = __shfl(bd[2][q], src);
            float bd0 = (cc < 16) ? b0 : b1;
            float bd1 = (cc < 16) ? b1 : b2;
            float s0 = (sc[0][q] + bd0) * 0.125f;
            float s1 = (sc[1][q] + bd1) * 0.125f;
            if (j0 + li > i + MLENC)      s0 = -1e30f;
            if (j0 + 16 + li > i + MLENC) s1 = -1e30f;
            float mx = fmaxf(s0, s1);
#pragma unroll
            for (int off = 1; off < 16; off <<= 1) mx = fmaxf(mx, __shfl_xor(mx, off));
            float mnew = fmaxf(mrun[q], mx);
            float p0 = __expf(s0 - mnew);
            float p1 = __expf(s1 - mnew);
            float ps = p0 + p1;
#pragma unroll
            for (int off = 1; off < 16; off <<= 1) ps += __shfl_xor(ps, off);
            float alpha = __expf(mrun[q] - mnew);
            srun[q] = srun[q] * alpha + ps;
            mrun[q] = mnew;
            av[q] = alpha; p0v[q] = p0; p1v[q] = p1;
        }
#pragma unroll
        for (int nf = 0; nf < 4; ++nf)
#pragma unroll
            for (int q = 0; q < 4; ++q) o[nf][q] *= av[q];

        // P -> LDS (D-layout scatter), read back as A-frag (same-wave, in-order)
        short* pw = &Pl[wid][0];
#pragma unroll
        for (int q = 0; q < 4; ++q) {
            pw[(4 * g + q) * 44 + li]      = f2bf(p0v[q]);
            pw[(4 * g + q) * 44 + 16 + li] = f2bf(p1v[q]);
        }
        bf16x8 pa = *(const bf16x8*)&pw[li * 44 + g * 8];
#pragma unroll
        for (int nf = 0; nf < 4; ++nf) {
            bf16x8 vf = *(const bf16x8*)&Vt[cur][(nf * 16 + li) * 40 + g * 8];
            o[nf] = __builtin_amdgcn_mfma_f32_16x16x32_bf16(pa, vf, o[nf], 0, 0, 0);
        }
        cur ^= 1;
    }

    float inv[4];
#pragma unroll
    for (int q = 0; q < 4; ++q) inv[q] = 1.0f / srun[q];
#pragma unroll
    for (int nf = 0; nf < 4; ++nf)
#pragma unroll
        for (int q = 0; q < 4; ++q) {
            int i = i0w + 4 * g + q;
            ctx[(size_t)(i * BSZC + b) * 1024 + n * 64 + nf * 16 + li] = f2bf(o[nf][q] * inv[q]);
        }
}

// ---------------------------------------------------------------------------
// LayerNorm(w + attn_out) * gamma + beta -> FLOAT32 out. One wave per row.
__launch_bounds__(256)
__global__ void ln_k(const float* __restrict__ attn, const float* __restrict__ win,
                     const float* __restrict__ gamma, const float* __restrict__ beta,
                     float* __restrict__ out)
{
    const int wid = threadIdx.x >> 6, lane = threadIdx.x & 63;
    const int m = blockIdx.x * 4 + wid;
    const float* ap = attn + (size_t)m * 1024 + lane * 16;
    const float* wp = win + (size_t)m * 1024 + lane * 16;

    f32x4 A[4], W[4];
#pragma unroll
    for (int t = 0; t < 4; ++t) {
        A[t] = *(const f32x4*)(ap + 4 * t);
        W[t] = *(const f32x4*)(wp + 4 * t);
    }
    float x[16];
#pragma unroll
    for (int t = 0; t < 4; ++t)
#pragma unroll
        for (int c = 0; c < 4; ++c) x[4 * t + c] = A[t][c] + W[t][c];

    float s = 0.f;
#pragma unroll
    for (int e = 0; e < 16; ++e) s += x[e];
#pragma unroll
    for (int off = 1; off < 64; off <<= 1) s += __shfl_xor(s, off);
    float mu = s * (1.0f / 1024.0f);
    float vs = 0.f;
#pragma unroll
    for (int e = 0; e < 16; ++e) { float dd = x[e] - mu; vs += dd * dd; }
#pragma unroll
    for (int off = 1; off < 64; off <<= 1) vs += __shfl_xor(vs, off);
    float rstd = rsqrtf(vs * (1.0f / 1024.0f) + 1e-5f);

    f32x4 G[4], Bt[4];
#pragma unroll
    for (int t = 0; t < 4; ++t) {
        G[t]  = *(const f32x4*)(gamma + lane * 16 + 4 * t);
        Bt[t] = *(const f32x4*)(beta + lane * 16 + 4 * t);
    }
#pragma unroll
    for (int t = 0; t < 4; ++t) {
        f32x4 y;
#pragma unroll
        for (int c = 0; c < 4; ++c)
            y[c] = (x[4 * t + c] - mu) * rstd * G[t][c] + Bt[t][c];
        *(f32x4*)(out + (size_t)m * 1024 + lane * 16 + 4 * t) = y;
    }
}

// ---------------------------------------------------------------------------
extern "C" void kernel_launch(void* const* d_in, const int* in_sizes, int n_in,
                              void* d_out, int out_size, void* d_ws, size_t ws_size,
                              hipStream_t stream)
{
    const float* w     = (const float*)d_in[0];   // [512,16,1024]
    const float* r     = (const float*)d_in[1];   // [1024,1024]
    const float* rwb   = (const float*)d_in[2];   // [16,64]
    const float* rrb   = (const float*)d_in[3];   // [16,64]
    const float* mems  = (const float*)d_in[4];   // [512,16,1024]
    // d_in[5] attn_mask: unused (mask computed analytically: j > i + MLEN)
    const float* Wqkv  = (const float*)d_in[6];   // [1024,3072]
    const float* Wr    = (const float*)d_in[7];   // [1024,1024]
    const float* Wo    = (const float*)d_in[8];   // [1024,1024]
    const float* gamma = (const float*)d_in[9];   // [1024]
    const float* beta  = (const float*)d_in[10];  // [1024]
    float* out = (float*)d_out;                   // FLOAT32 output

    // ws layout (peak 98 MB)
    char* p = (char*)d_ws;
    short* qws = (short*)p; p += (size_t)BSZC * NHEADC * QLENC * 64 * 2;  // 16 MB
    short* qrs = (short*)p; p += (size_t)BSZC * NHEADC * QLENC * 64 * 2;  // 16 MB
    short* kks = (short*)p; p += (size_t)BSZC * NHEADC * KLENC * 64 * 2;  // 32 MB
    short* vvs = (short*)p; p += (size_t)BSZC * NHEADC * KLENC * 64 * 2;  // 32 MB
    short* rks = (short*)p; p += (size_t)NHEADC * KLENC * 64 * 2;         //  2 MB
    short* ctx = (short*)d_out;   // bf16 ctx in d_out's first 16 MB (f32 buffer = 33.5 MB)
    float* att = (float*)d_ws;    // 32 MB alias over qws+qrs (dead after attn_k)

    gemm_k<0><<<dim3(128, 24), 256, 0, stream>>>(mems, w, Wqkv, rwb, rrb,
                                                 qws, qrs, kks, vvs, nullptr, 1024, 3072);
    gemm_k<1><<<dim3(8, 8), 256, 0, stream>>>(r, nullptr, Wr, nullptr, nullptr,
                                              rks, nullptr, nullptr, nullptr, nullptr, 1024, 1024);
    attn_k<<<dim3(8, NHEADC, BSZC), 256, 0, stream>>>(qws, qrs, kks, vvs, rks, ctx);
    gemm_k<2><<<dim3(64, 8), 256, 0, stream>>>(ctx, nullptr, Wo, nullptr, nullptr,
                                               nullptr, nullptr, nullptr, nullptr, att, 1024, 1024);
    ln_k<<<2048, 256, 0, stream>>>(att, w, gamma, beta, out);
}